// Round 1
// baseline (712.151 us; speedup 1.0000x reference)
//
#include <hip/hip_runtime.h>
#include <math.h>

// Problem constants (from reference setup_inputs)
#define B   64      // batch
#define P   64      // pool_size
#define L   5       // prompt_len
#define D   768     // embed_dim
#define K   5       // topk
#define S   2048    // seq_len
#define SOUT (K*L + S)   // 2073 output seq
#define EPS 1e-12f

// ---------------- Kernel 1: inverse L2 norms for prompt_key (rows 0..63) and
// cls_feature (rows 64..127). rinv[r] = rsqrt(max(sum sq, eps)). ----------------
__global__ void norms_kernel(const float* __restrict__ key,
                             const float* __restrict__ cls,
                             float* __restrict__ rinv) {
    const int r = blockIdx.x;                       // 0..127
    const float* src = (r < P) ? (key + (size_t)r * D)
                               : (cls + (size_t)(r - P) * D);
    const int t = threadIdx.x;                      // 256 threads
    float s = 0.f;
    for (int i = t; i < D; i += 256) { float v = src[i]; s += v * v; }
    // wave (64-lane) reduce
    for (int off = 32; off > 0; off >>= 1) s += __shfl_down(s, off);
    __shared__ float smem[4];
    if ((t & 63) == 0) smem[t >> 6] = s;
    __syncthreads();
    if (t == 0) {
        float tot = smem[0] + smem[1] + smem[2] + smem[3];
        rinv[r] = rsqrtf(fmaxf(tot, EPS));
    }
}

// ---------------- Kernel 2: sim row + top-5 indices. One block (1 wave, 64
// threads) per batch row b; lane p computes sim[b][p]; 5 rounds of wave-wide
// argmax (ties -> lowest index, matching lax.top_k). ----------------
__global__ void sim_topk_kernel(const float* __restrict__ key,
                                const float* __restrict__ cls,
                                const float* __restrict__ rinv,
                                int* __restrict__ idx_out) {
    const int b = blockIdx.x;       // 0..63
    const int p = threadIdx.x;      // 0..63 (one wave)
    const float* q = cls + (size_t)b * D;
    const float* k = key + (size_t)p * D;
    float acc = 0.f;
    for (int d = 0; d < D; ++d) acc += q[d] * k[d];
    float sim = acc * rinv[P + b] * rinv[p];
    for (int kk = 0; kk < K; ++kk) {
        float v = sim;
        int   id = p;
        for (int off = 32; off > 0; off >>= 1) {
            float ov = __shfl_down(v, off);
            int   oi = __shfl_down(id, off);
            if (ov > v || (ov == v && oi < id)) { v = ov; id = oi; }
        }
        int win = __shfl(id, 0);
        if (p == 0) idx_out[b * K + kk] = win;
        if (p == win) sim = -INFINITY;   // exclude winner for next round
    }
}

// ---------------- Kernel 3: loss = sum(kn * qn) / B (rows paired b<->b). ----------------
__global__ void loss_kernel(const float* __restrict__ key,
                            const float* __restrict__ cls,
                            const float* __restrict__ rinv,
                            float* __restrict__ out_loss) {
    const int t = threadIdx.x;    // 256 threads, 1 block
    float s = 0.f;
    for (int i = t; i < B * D; i += 256) {
        int b = i / D;
        s += key[i] * cls[i] * rinv[b] * rinv[P + b];
    }
    for (int off = 32; off > 0; off >>= 1) s += __shfl_down(s, off);
    __shared__ float smem[4];
    if ((t & 63) == 0) smem[t >> 6] = s;
    __syncthreads();
    if (t == 0) {
        float tot = smem[0] + smem[1] + smem[2] + smem[3];
        *out_loss = tot / (float)B;
    }
}

// ---------------- Kernel 4: gather selected prompts into output head.
// block = (b, kk); copies prompt[idx[b][kk]] (L*D floats) to out[b, kk*L : kk*L+L, :]. ----------------
__global__ void gather_kernel(const float* __restrict__ prompt,
                              const int* __restrict__ idx,
                              float* __restrict__ out) {
    const int bk = blockIdx.x;            // 0..B*K-1
    const int b  = bk / K;
    const int kk = bk % K;
    const int pi = idx[b * K + kk];
    const float4* src = (const float4*)(prompt + (size_t)pi * L * D);
    float4* dst = (float4*)(out + (size_t)b * SOUT * D + (size_t)kk * L * D);
    const int nv = L * D / 4;             // 960 float4
    for (int i = threadIdx.x; i < nv; i += 256) dst[i] = src[i];
}

// ---------------- Kernel 5: bulk copy x_embed into output tail.
// Per-batch contiguous chunk of S*D floats -> out[b, K*L:, :]. ----------------
__global__ void copy_kernel(const float* __restrict__ x,
                            float* __restrict__ out) {
    const int b = blockIdx.y;
    const float4* __restrict__ src = (const float4*)(x + (size_t)b * S * D);
    float4* __restrict__ dst = (float4*)(out + (size_t)b * SOUT * D + (size_t)(K * L) * D);
    const int nv = S * D / 4;             // 393216 float4 per batch
    int i = blockIdx.x * blockDim.x + threadIdx.x;
    const int stride = gridDim.x * blockDim.x;
    for (; i < nv; i += stride) dst[i] = src[i];
}

extern "C" void kernel_launch(void* const* d_in, const int* in_sizes, int n_in,
                              void* d_out, int out_size, void* d_ws, size_t ws_size,
                              hipStream_t stream) {
    const float* x_embed    = (const float*)d_in[0];   // (B, S, D)
    const float* cls        = (const float*)d_in[1];   // (B, D)
    const float* prompt     = (const float*)d_in[2];   // (P, L, D)
    const float* prompt_key = (const float*)d_in[3];   // (P, D)
    float* out = (float*)d_out;                        // res (B*SOUT*D) then loss (1)

    // workspace layout: rinv[0..127] floats, then idx[B*K] ints
    float* rinv = (float*)d_ws;
    int*   idx  = (int*)((char*)d_ws + 128 * sizeof(float));

    const size_t res_elems = (size_t)B * SOUT * D;     // 101,892,096
    float* out_loss = out + res_elems;

    norms_kernel<<<dim3(P + B), dim3(256), 0, stream>>>(prompt_key, cls, rinv);
    sim_topk_kernel<<<dim3(B), dim3(64), 0, stream>>>(prompt_key, cls, rinv, idx);
    loss_kernel<<<dim3(1), dim3(256), 0, stream>>>(prompt_key, cls, rinv, out_loss);
    gather_kernel<<<dim3(B * K), dim3(256), 0, stream>>>(prompt, idx, out);
    copy_kernel<<<dim3(384, B), dim3(256), 0, stream>>>(x_embed, out);
}